// Round 1
// 705.526 us; speedup vs baseline: 1.0314x; 1.0314x over previous
//
#include <hip/hip_runtime.h>
#include <hip/hip_fp16.h>

#define BB 512
#define TT 512
#define EE 100
#define HH 40
#define GG 120   // 3*HH
#define TC 64    // timesteps per chunk
#define NC 8     // chunks

typedef _Float16 h2_t __attribute__((ext_vector_type(2)));

__device__ __forceinline__ float fdot2_(h2_t a, h2_t b, float c) {
    return __builtin_amdgcn_fdot2(a, b, c, false);
}
__device__ __forceinline__ h2_t pack2_(float x, float y) {
    h2_t r; r[0] = (_Float16)x; r[1] = (_Float16)y; return r;
}
__device__ __forceinline__ float sigmoid_(float x) {
    return 1.0f / (1.0f + __expf(-x));
}
__device__ __forceinline__ float tanhfast_(float x) {
    float e = __expf(2.0f * x);
    return 1.0f - 2.0f / (e + 1.0f);
}

// Round-10 model: rocprof shows mixed dispatches ~42us = 64 steps x ~1575cy,
// vs a ~300cy static dep chain (LDS h-broadcast + GEMV + nonlin). VALUBusy
// 34% / Occ 16% => latency-stalled scan. The unhidden term is the gxR load:
// gx is produced by the PREVIOUS dispatch's GEMM on other XCDs, so scan
// reads it from L3/HBM (~500-900cy); a 1-deep prefetch caps hiding at one
// step-time. Fixes this round:
//  (1) 4-deep gx register prefetch, main loop unrolled x4 with NAMED slots
//      (q0..q3) so all indices are compile-time (no scratch). Load now has
//      ~4 step-times to land -> off the critical path.
//  (2) __launch_bounds__(256,4): GEMM can reach 4 blocks/CU (LDS 4x26KB ok,
//      VGPR cap 128 >= ~95) in case the gather-GEMM is co-limiting; scan
//      keeps s_setprio(3) so extra GEMM waves only use scan stall cycles.
// Everything else = round-9 structure: 1 chain/wave, fp16 Whh in 60 VGPRs,
// length-aware step range, fused pooling on layer 1.
template<int K, bool GATHER>
__global__ __launch_bounds__(256, 4) void fused_kernel(
    const int cg, const int cs, const int nScan,
    const int* __restrict__ text, const float* __restrict__ emb,
    const __half* __restrict__ Xh,
    const float* __restrict__ Wf, const float* __restrict__ bf,
    const float* __restrict__ Wb, const float* __restrict__ bb,
    __half* __restrict__ gxW, const __half* __restrict__ gxR,
    const float* __restrict__ WhhF, const float* __restrict__ bhhF,
    const float* __restrict__ WhhB, const float* __restrict__ bhhB,
    const int* __restrict__ lens,
    __half* __restrict__ out0,
    float* __restrict__ hcar, float* __restrict__ hlast,
    float* __restrict__ sumb, float* __restrict__ maxb)
{
    constexpr int K2 = K / 2;
    __shared__ h2_t Xs2[K2 * 64];
    __shared__ h2_t Ws2[K2 * 64];
    __shared__ __align__(16) _Float16 hsh[4][48];
    const int tid = threadIdx.x;

    if ((int)blockIdx.x < nScan) {
        // ============ scan: one wave = one (batch,dir) chain ============
        __builtin_amdgcn_s_setprio(3);
        const int wave = tid >> 6, j = tid & 63;
        if (j >= HH) return;
        const int chain = blockIdx.x * 4 + wave;   // 0..1023
        const int dir = chain >> 9;
        const int b   = chain & (BB - 1);
        const float* Whh = dir ? WhhB : WhhF;
        const float* bhh = dir ? bhhB : bhhF;

        // Whh rows {j,40+j,80+j} packed half2: 60 VGPRs, resident
        h2_t Wr[HH/2], Wz[HH/2], Wn[HH/2];
        {
            const float4* r4 = (const float4*)(Whh + (size_t)(0*HH + j) * HH);
            const float4* z4 = (const float4*)(Whh + (size_t)(1*HH + j) * HH);
            const float4* n4 = (const float4*)(Whh + (size_t)(2*HH + j) * HH);
            #pragma unroll
            for (int q = 0; q < HH/4; ++q) {
                float4 v;
                v = r4[q]; Wr[2*q] = pack2_(v.x,v.y); Wr[2*q+1] = pack2_(v.z,v.w);
                v = z4[q]; Wz[2*q] = pack2_(v.x,v.y); Wz[2*q+1] = pack2_(v.z,v.w);
                v = n4[q]; Wn[2*q] = pack2_(v.x,v.y); Wn[2*q+1] = pack2_(v.z,v.w);
            }
        }
        const float br = bhh[j], bz = bhh[HH + j], bn = bhh[2*HH + j];
        const int len = lens[b];
        const int chunk = dir ? (NC - 1 - cs) : cs;
        const int tbase = chunk * TC;

        // executed step range: all executed steps have t < len
        int sBeg, sEnd;
        if (dir == 0) { sBeg = 0; sEnd = min(TC, max(0, len - tbase)); }
        else          { sBeg = max(0, tbase + TC - len); sEnd = TC; }

        float h = (cs == 0) ? 0.0f : hcar[(size_t)(dir * BB + b) * HH + j];
        hsh[wave][j] = (_Float16)h;
        float psum = 0.0f, pmax = -3.4e38f;
        const size_t gxRow = ((size_t)dir * BB + b) * TC;
        const float4* h4 = (const float4*)hsh[wave];

        struct G3 { __half r, z, n; };
        auto ldg3 = [&](int sc) -> G3 {
            const int tl = dir ? (TC - 1 - sc) : sc;
            const __half* gp = gxR + (gxRow + tl) * GG;
            G3 g; g.r = gp[j]; g.z = gp[HH + j]; g.n = gp[2*HH + j];
            return g;
        };
        constexpr int PF = 4;   // prefetch depth: hides ~4 step-times of latency
        auto step = [&](int s, G3& g, bool pf) {
            G3 nx;
            if (pf) nx = ldg3(min(s + PF, sEnd - 1));  // clamped: always in-slab
            const int tloc = dir ? (TC - 1 - s) : s;
            // GEMV: 60 dot2, two partial accumulators per gate
            float r0 = br, r1 = 0.f, z0 = bz, z1 = 0.f, n0 = bn, n1 = 0.f;
            #pragma unroll
            for (int q = 0; q < 5; ++q) {
                union { float4 f; h2_t hh[4]; } u;
                u.f = h4[q];
                r0 = fdot2_(Wr[4*q+0], u.hh[0], r0);
                z0 = fdot2_(Wz[4*q+0], u.hh[0], z0);
                n0 = fdot2_(Wn[4*q+0], u.hh[0], n0);
                r1 = fdot2_(Wr[4*q+1], u.hh[1], r1);
                z1 = fdot2_(Wz[4*q+1], u.hh[1], z1);
                n1 = fdot2_(Wn[4*q+1], u.hh[1], n1);
                r0 = fdot2_(Wr[4*q+2], u.hh[2], r0);
                z0 = fdot2_(Wz[4*q+2], u.hh[2], z0);
                n0 = fdot2_(Wn[4*q+2], u.hh[2], n0);
                r1 = fdot2_(Wr[4*q+3], u.hh[3], r1);
                z1 = fdot2_(Wz[4*q+3], u.hh[3], z1);
                n1 = fdot2_(Wn[4*q+3], u.hh[3], n1);
            }
            const float rr = sigmoid_(__half2float(g.r) + r0 + r1);
            const float zz = sigmoid_(__half2float(g.z) + z0 + z1);
            const float nn = tanhfast_(__half2float(g.n) + rr * (n0 + n1));
            const float hn = (1.0f - zz) * nn + zz * h;
            h = hn;                        // all executed steps are valid
            hsh[wave][j] = (_Float16)h;    // broadcast for next step
            if (GATHER) {  // layer 0: materialize out0 fp16 (valid t only)
                const int t = tbase + tloc;
                out0[((size_t)b * TT + t) * (2*HH) + dir*HH + j] = __float2half(hn);
            } else {       // layer 1: fused pooling (valid t only)
                psum += hn;
                pmax = fmaxf(pmax, hn);
            }
            if (pf) g = nx;
        };

        G3 q0 = {}, q1 = {}, q2 = {}, q3 = {};
        if (sBeg < sEnd) {
            q0 = ldg3(sBeg);
            q1 = ldg3(min(sBeg + 1, sEnd - 1));
            q2 = ldg3(min(sBeg + 2, sEnd - 1));
            q3 = ldg3(min(sBeg + 3, sEnd - 1));
        }
        int s = sBeg;
        for (; s + PF <= sEnd; s += PF) {
            step(s + 0, q0, true);
            step(s + 1, q1, true);
            step(s + 2, q2, true);
            step(s + 3, q3, true);
        }
        if (s     < sEnd) step(s,     q0, false);
        if (s + 1 < sEnd) step(s + 1, q1, false);
        if (s + 2 < sEnd) step(s + 2, q2, false);

        hcar[(size_t)(dir * BB + b) * HH + j] = h;
        const int layer = GATHER ? 0 : 1;
        if (cs == NC - 1)
            hlast[((size_t)(layer * 2 + dir) * BB + b) * HH + j] = h;
        if (!GATHER) {
            const size_t pi = (size_t)b * (2*HH) + dir*HH + j;
            if (cs == 0) { sumb[pi] = psum;  maxb[pi] = pmax; }
            else         { sumb[pi] += psum; maxb[pi] = fmaxf(maxb[pi], pmax); }
        }
        return;
    }

    // ================= gemm (fp16 dot2), prio 0 =================
    __builtin_amdgcn_s_setprio(0);
    const int gid = blockIdx.x - nScan;
    const int b   = gid & (BB - 1);
    const int ct  = (gid >> 9) & 1;
    const int dir = gid >> 10;
    const int chunk = dir ? (NC - 1 - cg) : cg;
    const int tbase = chunk * TC;
    if (tbase >= lens[b]) return;   // tile fully past len: gx never read
    const float* W    = dir ? Wb : Wf;
    const float* bias = dir ? bb : bf;
    const int c0 = ct * 64;

    // stage X fp16 k-pair-major: Xs2[k2][r]
    if (GATHER) {
        constexpr int KQ = K / 4;
        for (int idx = tid; idx < 64 * KQ; idx += 256) {
            const int r = idx & 63, q = idx >> 6;
            const int tok = text[b * TT + tbase + r];
            const float4 v = ((const float4*)emb)[(size_t)tok * KQ + q];
            Xs2[(2*q+0)*64 + r] = pack2_(v.x, v.y);
            Xs2[(2*q+1)*64 + r] = pack2_(v.z, v.w);
        }
    } else {
        constexpr int KQ8 = K / 8;
        for (int idx = tid; idx < 64 * KQ8; idx += 256) {
            const int r = idx & 63, q = idx >> 6;
            union { float4 f; h2_t h[4]; } u;
            u.f = ((const float4*)Xh)[((size_t)b * TT + tbase + r) * KQ8 + q];
            #pragma unroll
            for (int i2 = 0; i2 < 4; ++i2)
                Xs2[(4*q + i2)*64 + r] = u.h[i2];
        }
    }
    // stage W fp16 k-pair-major: Ws2[k2][c]
    {
        constexpr int KQ = K / 4;
        for (int idx = tid; idx < 64 * KQ; idx += 256) {
            const int c = idx & 63, q = idx >> 6;
            float4 v = make_float4(0.f,0.f,0.f,0.f);
            if (c0 + c < GG) v = ((const float4*)W)[(size_t)(c0 + c) * KQ + q];
            Ws2[(2*q+0)*64 + c] = pack2_(v.x, v.y);
            Ws2[(2*q+1)*64 + c] = pack2_(v.z, v.w);
        }
    }
    __syncthreads();

    const int tx = tid & 15, ty = tid >> 4;
    float acc[4][4] = {};
    #pragma unroll 2
    for (int k2 = 0; k2 < K2; ++k2) {
        union { float4 f; h2_t h[4]; } xa, wv;
        xa.f = *(const float4*)(Xs2 + k2*64 + (ty << 2));
        wv.f = *(const float4*)(Ws2 + k2*64 + (tx << 2));
        #pragma unroll
        for (int i = 0; i < 4; ++i)
            #pragma unroll
            for (int j2 = 0; j2 < 4; ++j2)
                acc[i][j2] = fdot2_(xa.h[i], wv.h[j2], acc[i][j2]);
    }

    const int c = c0 + (tx << 2);
    if (c < GG) {
        const float b0v = bias[c], b1v = bias[c+1], b2v = bias[c+2], b3v = bias[c+3];
        const size_t rowB = ((size_t)dir * BB + b) * TC;
        #pragma unroll
        for (int i = 0; i < 4; ++i) {
            const int tloc = (ty << 2) + i;
            union { float2 f; __half2 h[2]; } u;
            u.h[0] = __floats2half2_rn(acc[i][0] + b0v, acc[i][1] + b1v);
            u.h[1] = __floats2half2_rn(acc[i][2] + b2v, acc[i][3] + b3v);
            *(float2*)(gxW + (rowB + tloc) * GG + c) = u.f;
        }
    }
}

// pool_cat = [hb1, hf1, hb0, hf0, avg(80), max(80)] -> fc1(128) -> lrelu -> fc2(1)
__global__ __launch_bounds__(128) void fc_kernel(
    const float* __restrict__ hlast, const float* __restrict__ sumb,
    const float* __restrict__ maxb, const int* __restrict__ lens,
    const float* __restrict__ fc1W, const float* __restrict__ fc1b,
    const float* __restrict__ fc2W, const float* __restrict__ fc2b,
    float* __restrict__ out)
{
    __shared__ float pool[8 * HH];
    __shared__ float red[128];
    const int b = blockIdx.x, tid = threadIdx.x;
    if (tid < HH) {
        pool[tid]        = hlast[(size_t)(3*BB + b) * HH + tid]; // hb1
        pool[HH + tid]   = hlast[(size_t)(2*BB + b) * HH + tid]; // hf1
        pool[2*HH + tid] = hlast[(size_t)(1*BB + b) * HH + tid]; // hb0
        pool[3*HH + tid] = hlast[(size_t)(0*BB + b) * HH + tid]; // hf0
    }
    const float invLen = 1.0f / (float)lens[b];
    if (tid < 2*HH) {
        pool[4*HH + tid] = sumb[(size_t)b * 2*HH + tid] * invLen;
        pool[6*HH + tid] = maxb[(size_t)b * 2*HH + tid];
    }
    __syncthreads();
    float acc = fc1b[tid];
    for (int k = 0; k < 8*HH; ++k)
        acc = fmaf(pool[k], fc1W[(size_t)tid * (8*HH) + k], acc);
    float v = (acc >= 0.0f) ? acc : 0.01f * acc;
    red[tid] = v * fc2W[tid];
    __syncthreads();
    for (int s = 64; s > 0; s >>= 1) {
        if (tid < s) red[tid] += red[tid + s];
        __syncthreads();
    }
    if (tid == 0) out[b] = red[0] + fc2b[0];
}

extern "C" void kernel_launch(void* const* d_in, const int* in_sizes, int n_in,
                              void* d_out, int out_size, void* d_ws, size_t ws_size,
                              hipStream_t stream) {
    const int*   text  = (const int*)d_in[0];
    const int*   lens  = (const int*)d_in[1];
    const float* emb   = (const float*)d_in[2];
    const float* Wih0f = (const float*)d_in[3];
    const float* Whh0f = (const float*)d_in[4];
    const float* bih0f = (const float*)d_in[5];
    const float* bhh0f = (const float*)d_in[6];
    const float* Wih0b = (const float*)d_in[7];
    const float* Whh0b = (const float*)d_in[8];
    const float* bih0b = (const float*)d_in[9];
    const float* bhh0b = (const float*)d_in[10];
    const float* Wih1f = (const float*)d_in[11];
    const float* Whh1f = (const float*)d_in[12];
    const float* bih1f = (const float*)d_in[13];
    const float* bhh1f = (const float*)d_in[14];
    const float* Wih1b = (const float*)d_in[15];
    const float* Whh1b = (const float*)d_in[16];
    const float* bih1b = (const float*)d_in[17];
    const float* bhh1b = (const float*)d_in[18];
    const float* fc1W  = (const float*)d_in[19];
    const float* fc1b  = (const float*)d_in[20];
    const float* fc2W  = (const float*)d_in[21];
    const float* fc2b  = (const float*)d_in[22];
    float* out = (float*)d_out;

    // ws: gx double-buffer fp16 (2 x 15.73MB) | out0 fp16 (41.94MB) | small
    char* p = (char*)d_ws;
    const size_t gxB = (size_t)2 * BB * TC * GG * sizeof(__half);
    __half* gxb0  = (__half*)p;  p += gxB;
    __half* gxb1  = (__half*)p;  p += gxB;
    __half* out0  = (__half*)p;  p += (size_t)BB * TT * 2 * HH * sizeof(__half);
    float*  hcar  = (float*)p;   p += (size_t)2 * BB * HH * sizeof(float);
    float*  hlast = (float*)p;   p += (size_t)4 * BB * HH * sizeof(float);
    float*  sumb  = (float*)p;   p += (size_t)BB * 2 * HH * sizeof(float);
    float*  maxb  = (float*)p;
    __half* gxb[2] = { gxb0, gxb1 };

    const int NG = BB * 2 * 2;   // 2048 gemm blocks
    const int NS = 256;          // 1024 chains / 4 waves per block

    // ---- layer 0 ----
    fused_kernel<EE, true><<<NG, 256, 0, stream>>>(0, 0, 0,
        text, emb, nullptr, Wih0f, bih0f, Wih0b, bih0b,
        gxb[0], gxb[0], Whh0f, bhh0f, Whh0b, bhh0b,
        lens, out0, hcar, hlast, sumb, maxb);
    for (int ci = 1; ci < NC; ++ci)
        fused_kernel<EE, true><<<NS + NG, 256, 0, stream>>>(ci, ci - 1, NS,
            text, emb, nullptr, Wih0f, bih0f, Wih0b, bih0b,
            gxb[ci & 1], gxb[(ci - 1) & 1], Whh0f, bhh0f, Whh0b, bhh0b,
            lens, out0, hcar, hlast, sumb, maxb);
    fused_kernel<EE, true><<<NS, 256, 0, stream>>>(0, NC - 1, NS,
        text, emb, nullptr, Wih0f, bih0f, Wih0b, bih0b,
        gxb[0], gxb[(NC - 1) & 1], Whh0f, bhh0f, Whh0b, bhh0b,
        lens, out0, hcar, hlast, sumb, maxb);

    // ---- layer 1 ----
    fused_kernel<2*HH, false><<<NG, 256, 0, stream>>>(0, 0, 0,
        text, emb, out0, Wih1f, bih1f, Wih1b, bih1b,
        gxb[0], gxb[0], Whh1f, bhh1f, Whh1b, bhh1b,
        lens, out0, hcar, hlast, sumb, maxb);
    for (int ci = 1; ci < NC; ++ci)
        fused_kernel<2*HH, false><<<NS + NG, 256, 0, stream>>>(ci, ci - 1, NS,
            text, emb, out0, Wih1f, bih1f, Wih1b, bih1b,
            gxb[ci & 1], gxb[(ci - 1) & 1], Whh1f, bhh1f, Whh1b, bhh1b,
            lens, out0, hcar, hlast, sumb, maxb);
    fused_kernel<2*HH, false><<<NS, 256, 0, stream>>>(0, NC - 1, NS,
        text, emb, out0, Wih1f, bih1f, Wih1b, bih1b,
        gxb[0], gxb[(NC - 1) & 1], Whh1f, bhh1f, Whh1b, bhh1b,
        lens, out0, hcar, hlast, sumb, maxb);

    // ---- head ----
    fc_kernel<<<BB, 128, 0, stream>>>(hlast, sumb, maxb, lens,
        fc1W, fc1b, fc2W, fc2b, out);
}

// Round 2
// 678.073 us; speedup vs baseline: 1.0732x; 1.0405x over previous
//
#include <hip/hip_runtime.h>
#include <hip/hip_fp16.h>

#define BB 512
#define TT 512
#define EE 100
#define HH 40
#define GG 120   // 3*HH
#define TC 64    // timesteps per chunk
#define NC 8     // chunks

typedef _Float16 h2_t __attribute__((ext_vector_type(2)));
typedef _Float16 h8_t __attribute__((ext_vector_type(8)));

__device__ __forceinline__ float fdot2_(h2_t a, h2_t b, float c) {
    return __builtin_amdgcn_fdot2(a, b, c, false);
}
__device__ __forceinline__ h2_t pack2_(float x, float y) {
    h2_t r; r[0] = (_Float16)x; r[1] = (_Float16)y; return r;
}
__device__ __forceinline__ float sigmoid_(float x) {
    return 1.0f / (1.0f + __expf(-x));
}
__device__ __forceinline__ float tanhfast_(float x) {
    float e = __expf(2.0f * x);
    return 1.0f - 2.0f / (e + 1.0f);
}

// Round-11 model: r1 profile shows the GEMM-ONLY head dispatch (45.2us) is as
// slow as mixed => the pipeline is GEMM-limited; scan hides under it. GEMM is
// 11% of dot2 peak, 11% HBM, 0 bank conflicts, VALUBusy 31% -> dominated by
// staging instructions (fp32->fp16 cvt x6400/block, 25x-redundant token loads)
// and their latency. Also VGPR_Count=64 proves the scan's 60 Whh "resident
// registers" were never resident (arrays got demoted). Fixes:
//  (1) prep_kernel precomputes: emb -> fp16 (10MB), Wih -> fp16 PRE-TRANSPOSED
//      into the exact k2-major LDS tile layout, Whh -> fp16 row-major.
//      GEMM W-stage becomes a raw float4 memcpy; X gather loads fp16 (half
//      bytes, zero cvt), one token load per thread.
//  (2) scan Whh held in 15 NAMED h8_t registers (no arrays -> allocator cannot
//      demote); gate slices via compile-time shufflevector.
// ws budget: fill kernels show ws >= 256MiB; tables add ~10.2MB on top of 74MB.
template<int K, bool GATHER>
__global__ __launch_bounds__(256, 4) void fused_kernel(
    const int cg, const int cs, const int nScan,
    const int* __restrict__ text, const __half* __restrict__ emb16,
    const __half* __restrict__ Xh,
    const h2_t* __restrict__ Wt,
    const float* __restrict__ bf, const float* __restrict__ bb,
    __half* __restrict__ gxW, const __half* __restrict__ gxR,
    const _Float16* __restrict__ WhhL,
    const float* __restrict__ bhhF, const float* __restrict__ bhhB,
    const int* __restrict__ lens,
    __half* __restrict__ out0,
    float* __restrict__ hcar, float* __restrict__ hlast,
    float* __restrict__ sumb, float* __restrict__ maxb)
{
    constexpr int K2 = K / 2;
    __shared__ __align__(16) h2_t Xs2[K2 * 64];
    __shared__ __align__(16) h2_t Ws2[K2 * 64];
    __shared__ __align__(16) _Float16 hsh[4][48];
    const int tid = threadIdx.x;

    if ((int)blockIdx.x < nScan) {
        // ============ scan: one wave = one (batch,dir) chain ============
        __builtin_amdgcn_s_setprio(3);
        const int wave = tid >> 6, j = tid & 63;
        if (j >= HH) return;
        const int chain = blockIdx.x * 4 + wave;   // 0..1023
        const int dir = chain >> 9;
        const int b   = chain & (BB - 1);
        const float* bhh = dir ? bhhB : bhhF;

        // Whh rows {j,40+j,80+j} as fp16 in 15 NAMED h8 registers (60 VGPRs).
        h8_t R0,R1,R2,R3,R4, Z0,Z1,Z2,Z3,Z4, N0,N1,N2,N3,N4;
        {
            const _Float16* wr = WhhL + (size_t)dir * 4800;
            const h8_t* pr = (const h8_t*)(wr + (size_t)j * 40);
            const h8_t* pz = (const h8_t*)(wr + (size_t)(40 + j) * 40);
            const h8_t* pn = (const h8_t*)(wr + (size_t)(80 + j) * 40);
            R0=pr[0]; R1=pr[1]; R2=pr[2]; R3=pr[3]; R4=pr[4];
            Z0=pz[0]; Z1=pz[1]; Z2=pz[2]; Z3=pz[3]; Z4=pz[4];
            N0=pn[0]; N1=pn[1]; N2=pn[2]; N3=pn[3]; N4=pn[4];
        }
        const float br = bhh[j], bz = bhh[HH + j], bn = bhh[2*HH + j];
        const int len = lens[b];
        const int chunk = dir ? (NC - 1 - cs) : cs;
        const int tbase = chunk * TC;

        // executed step range: all executed steps have t < len
        int sBeg, sEnd;
        if (dir == 0) { sBeg = 0; sEnd = min(TC, max(0, len - tbase)); }
        else          { sBeg = max(0, tbase + TC - len); sEnd = TC; }

        float h = (cs == 0) ? 0.0f : hcar[(size_t)(dir * BB + b) * HH + j];
        hsh[wave][j] = (_Float16)h;
        float psum = 0.0f, pmax = -3.4e38f;
        const size_t gxRow = ((size_t)dir * BB + b) * TC;
        const float4* h4 = (const float4*)hsh[wave];

        struct G3 { __half r, z, n; };
        auto ldg3 = [&](int sc) -> G3 {
            const int tl = dir ? (TC - 1 - sc) : sc;
            const __half* gp = gxR + (gxRow + tl) * GG;
            G3 g; g.r = gp[j]; g.z = gp[HH + j]; g.n = gp[2*HH + j];
            return g;
        };
#define SL(V,i) __builtin_shufflevector(V, V, 2*(i), 2*(i)+1)
#define DOTQ(Rq,Zq,Nq,U) \
        r0 = fdot2_(SL(Rq,0), U.hh[0], r0); \
        z0 = fdot2_(SL(Zq,0), U.hh[0], z0); \
        n0 = fdot2_(SL(Nq,0), U.hh[0], n0); \
        r1 = fdot2_(SL(Rq,1), U.hh[1], r1); \
        z1 = fdot2_(SL(Zq,1), U.hh[1], z1); \
        n1 = fdot2_(SL(Nq,1), U.hh[1], n1); \
        r0 = fdot2_(SL(Rq,2), U.hh[2], r0); \
        z0 = fdot2_(SL(Zq,2), U.hh[2], z0); \
        n0 = fdot2_(SL(Nq,2), U.hh[2], n0); \
        r1 = fdot2_(SL(Rq,3), U.hh[3], r1); \
        z1 = fdot2_(SL(Zq,3), U.hh[3], z1); \
        n1 = fdot2_(SL(Nq,3), U.hh[3], n1);

        constexpr int PF = 4;   // prefetch depth
        auto step = [&](int s, G3& g, bool pf) {
            G3 nx;
            if (pf) nx = ldg3(min(s + PF, sEnd - 1));  // clamped: always in-slab
            const int tloc = dir ? (TC - 1 - s) : s;
            float r0 = br, r1 = 0.f, z0 = bz, z1 = 0.f, n0 = bn, n1 = 0.f;
            union { float4 f; h2_t hh[4]; } u0, u1, u2, u3, u4;
            u0.f = h4[0]; u1.f = h4[1]; u2.f = h4[2]; u3.f = h4[3]; u4.f = h4[4];
            DOTQ(R0,Z0,N0,u0)
            DOTQ(R1,Z1,N1,u1)
            DOTQ(R2,Z2,N2,u2)
            DOTQ(R3,Z3,N3,u3)
            DOTQ(R4,Z4,N4,u4)
            const float rr = sigmoid_(__half2float(g.r) + r0 + r1);
            const float zz = sigmoid_(__half2float(g.z) + z0 + z1);
            const float nn = tanhfast_(__half2float(g.n) + rr * (n0 + n1));
            const float hn = (1.0f - zz) * nn + zz * h;
            h = hn;                        // all executed steps are valid
            hsh[wave][j] = (_Float16)h;    // broadcast for next step
            if (GATHER) {  // layer 0: materialize out0 fp16 (valid t only)
                const int t = tbase + tloc;
                out0[((size_t)b * TT + t) * (2*HH) + dir*HH + j] = __float2half(hn);
            } else {       // layer 1: fused pooling (valid t only)
                psum += hn;
                pmax = fmaxf(pmax, hn);
            }
            if (pf) g = nx;
        };

        G3 q0 = {}, q1 = {}, q2 = {}, q3 = {};
        if (sBeg < sEnd) {
            q0 = ldg3(sBeg);
            q1 = ldg3(min(sBeg + 1, sEnd - 1));
            q2 = ldg3(min(sBeg + 2, sEnd - 1));
            q3 = ldg3(min(sBeg + 3, sEnd - 1));
        }
        int s = sBeg;
        for (; s + PF <= sEnd; s += PF) {
            step(s + 0, q0, true);
            step(s + 1, q1, true);
            step(s + 2, q2, true);
            step(s + 3, q3, true);
        }
        if (s     < sEnd) step(s,     q0, false);
        if (s + 1 < sEnd) step(s + 1, q1, false);
        if (s + 2 < sEnd) step(s + 2, q2, false);

        hcar[(size_t)(dir * BB + b) * HH + j] = h;
        const int layer = GATHER ? 0 : 1;
        if (cs == NC - 1)
            hlast[((size_t)(layer * 2 + dir) * BB + b) * HH + j] = h;
        if (!GATHER) {
            const size_t pi = (size_t)b * (2*HH) + dir*HH + j;
            if (cs == 0) { sumb[pi] = psum;  maxb[pi] = pmax; }
            else         { sumb[pi] += psum; maxb[pi] = fmaxf(maxb[pi], pmax); }
        }
        return;
    }

    // ================= gemm (fp16 dot2), prio 0 =================
    __builtin_amdgcn_s_setprio(0);
    const int gid = blockIdx.x - nScan;
    const int b   = gid & (BB - 1);
    const int ct  = (gid >> 9) & 1;
    const int dir = gid >> 10;
    const int chunk = dir ? (NC - 1 - cg) : cg;
    const int tbase = chunk * TC;
    if (tbase >= lens[b]) return;   // tile fully past len: gx never read
    const float* bias = dir ? bb : bf;
    const int c0 = ct * 64;

    // stage X fp16 k-pair-major: Xs2[k2][r]
    if (GATHER) {
        // one token per thread (r = tid&63), fp16 emb rows, zero cvt
        const int r  = tid & 63;
        const int qg = tid >> 6;                      // 0..3
        const int tok = text[b * TT + tbase + r];
        const uint2* erow = (const uint2*)(emb16 + (size_t)tok * EE);
        for (int q = qg; q < EE/4; q += 4) {          // 25 uint2 per row
            const uint2 v = erow[q];
            union { unsigned u; h2_t h; } a, c2;
            a.u = v.x; c2.u = v.y;
            Xs2[(2*q+0)*64 + r] = a.h;
            Xs2[(2*q+1)*64 + r] = c2.h;
        }
    } else {
        constexpr int KQ8 = K / 8;
        for (int idx = tid; idx < 64 * KQ8; idx += 256) {
            const int r = idx & 63, q = idx >> 6;
            union { float4 f; h2_t h[4]; } u;
            u.f = ((const float4*)Xh)[((size_t)b * TT + tbase + r) * KQ8 + q];
            #pragma unroll
            for (int i2 = 0; i2 < 4; ++i2)
                Xs2[(4*q + i2)*64 + r] = u.h[i2];
        }
    }
    // stage W fp16: straight float4 copy of pre-transposed table
    {
        const h2_t* Wt2 = Wt + (size_t)(dir*2 + ct) * (K2*64);
        for (int idx = tid; idx < K2*16; idx += 256)
            ((float4*)Ws2)[idx] = ((const float4*)Wt2)[idx];
    }
    __syncthreads();

    const int tx = tid & 15, ty = tid >> 4;
    float acc[4][4] = {};
    #pragma unroll 5
    for (int k2 = 0; k2 < K2; ++k2) {
        union { float4 f; h2_t h[4]; } xa, wv;
        xa.f = *(const float4*)(Xs2 + k2*64 + (ty << 2));
        wv.f = *(const float4*)(Ws2 + k2*64 + (tx << 2));
        #pragma unroll
        for (int i = 0; i < 4; ++i)
            #pragma unroll
            for (int j2 = 0; j2 < 4; ++j2)
                acc[i][j2] = fdot2_(xa.h[i], wv.h[j2], acc[i][j2]);
    }

    const int c = c0 + (tx << 2);
    if (c < GG) {
        const float b0v = bias[c], b1v = bias[c+1], b2v = bias[c+2], b3v = bias[c+3];
        const size_t rowB = ((size_t)dir * BB + b) * TC;
        #pragma unroll
        for (int i = 0; i < 4; ++i) {
            const int tloc = (ty << 2) + i;
            union { float2 f; __half2 h[2]; } u;
            u.h[0] = __floats2half2_rn(acc[i][0] + b0v, acc[i][1] + b1v);
            u.h[1] = __floats2half2_rn(acc[i][2] + b2v, acc[i][3] + b3v);
            *(float2*)(gxW + (rowB + tloc) * GG + c) = u.f;
        }
    }
}

// Precompute fp16 tables: emb16 [V][100], Wih pre-transposed k2-major
// [lay][dir][ct][K2][64] h2, Whh fp16 row-major [lay*2+dir][120][40].
#define NE_EMB (50000 * 25)     // uint2 units of emb
#define NW_L0  (2*2*50*64)      // 12800 h2 entries
#define NW_L1  (2*2*40*64)      // 10240 h2 entries
#define NW_HH  (4*120*20)       // 9600 h2 entries
__global__ __launch_bounds__(256) void prep_kernel(
    const float* __restrict__ emb,
    const float* __restrict__ Wih0f, const float* __restrict__ Wih0b,
    const float* __restrict__ Wih1f, const float* __restrict__ Wih1b,
    const float* __restrict__ Whh0f, const float* __restrict__ Whh0b,
    const float* __restrict__ Whh1f, const float* __restrict__ Whh1b,
    __half* __restrict__ emb16, h2_t* __restrict__ Wt16,
    _Float16* __restrict__ Whh16)
{
    const int gid = blockIdx.x * 256 + threadIdx.x;
    if (gid < NE_EMB) {
        const int v = gid / 25, q = gid - v * 25;
        const float4 f = ((const float4*)emb)[(size_t)v * 25 + q];
        h2_t* dst = (h2_t*)(emb16 + (size_t)v * EE + q * 4);
        dst[0] = pack2_(f.x, f.y);
        dst[1] = pack2_(f.z, f.w);
        return;
    }
    int e = gid - NE_EMB;
    if (e < NW_L0) {            // layer0 Wih, K=100
        const int c = e & 63; const int t2 = e >> 6;
        const int k2 = t2 % 50; const int dc = t2 / 50;
        const int dir = dc >> 1, ct = dc & 1;
        const int col = ct * 64 + c;
        const float* W = dir ? Wih0b : Wih0f;
        float x0 = 0.f, x1 = 0.f;
        if (col < GG) { x0 = W[col*EE + 2*k2]; x1 = W[col*EE + 2*k2 + 1]; }
        Wt16[e] = pack2_(x0, x1);
        return;
    }
    e -= NW_L0;
    if (e < NW_L1) {            // layer1 Wih, K=80
        const int c = e & 63; const int t2 = e >> 6;
        const int k2 = t2 % 40; const int dc = t2 / 40;
        const int dir = dc >> 1, ct = dc & 1;
        const int col = ct * 64 + c;
        const float* W = dir ? Wih1b : Wih1f;
        float x0 = 0.f, x1 = 0.f;
        if (col < GG) { x0 = W[col*(2*HH) + 2*k2]; x1 = W[col*(2*HH) + 2*k2 + 1]; }
        Wt16[NW_L0 + e] = pack2_(x0, x1);
        return;
    }
    e -= NW_L1;
    if (e < NW_HH) {            // Whh fp16, 4 x [120][40]
        const int ld = e / 2400, rem = e - ld * 2400;
        const int row = rem / 20, kk = rem - row * 20;
        const float* W = (ld == 0) ? Whh0f : (ld == 1) ? Whh0b
                       : (ld == 2) ? Whh1f : Whh1b;
        ((h2_t*)Whh16)[e] = pack2_(W[row*HH + 2*kk], W[row*HH + 2*kk + 1]);
    }
}

// pool_cat = [hb1, hf1, hb0, hf0, avg(80), max(80)] -> fc1(128) -> lrelu -> fc2(1)
__global__ __launch_bounds__(128) void fc_kernel(
    const float* __restrict__ hlast, const float* __restrict__ sumb,
    const float* __restrict__ maxb, const int* __restrict__ lens,
    const float* __restrict__ fc1W, const float* __restrict__ fc1b,
    const float* __restrict__ fc2W, const float* __restrict__ fc2b,
    float* __restrict__ out)
{
    __shared__ float pool[8 * HH];
    __shared__ float red[128];
    const int b = blockIdx.x, tid = threadIdx.x;
    if (tid < HH) {
        pool[tid]        = hlast[(size_t)(3*BB + b) * HH + tid]; // hb1
        pool[HH + tid]   = hlast[(size_t)(2*BB + b) * HH + tid]; // hf1
        pool[2*HH + tid] = hlast[(size_t)(1*BB + b) * HH + tid]; // hb0
        pool[3*HH + tid] = hlast[(size_t)(0*BB + b) * HH + tid]; // hf0
    }
    const float invLen = 1.0f / (float)lens[b];
    if (tid < 2*HH) {
        pool[4*HH + tid] = sumb[(size_t)b * 2*HH + tid] * invLen;
        pool[6*HH + tid] = maxb[(size_t)b * 2*HH + tid];
    }
    __syncthreads();
    float acc = fc1b[tid];
    for (int k = 0; k < 8*HH; ++k)
        acc = fmaf(pool[k], fc1W[(size_t)tid * (8*HH) + k], acc);
    float v = (acc >= 0.0f) ? acc : 0.01f * acc;
    red[tid] = v * fc2W[tid];
    __syncthreads();
    for (int s = 64; s > 0; s >>= 1) {
        if (tid < s) red[tid] += red[tid + s];
        __syncthreads();
    }
    if (tid == 0) out[b] = red[0] + fc2b[0];
}

extern "C" void kernel_launch(void* const* d_in, const int* in_sizes, int n_in,
                              void* d_out, int out_size, void* d_ws, size_t ws_size,
                              hipStream_t stream) {
    const int*   text  = (const int*)d_in[0];
    const int*   lens  = (const int*)d_in[1];
    const float* emb   = (const float*)d_in[2];
    const float* Wih0f = (const float*)d_in[3];
    const float* Whh0f = (const float*)d_in[4];
    const float* bih0f = (const float*)d_in[5];
    const float* bhh0f = (const float*)d_in[6];
    const float* Wih0b = (const float*)d_in[7];
    const float* Whh0b = (const float*)d_in[8];
    const float* bih0b = (const float*)d_in[9];
    const float* bhh0b = (const float*)d_in[10];
    const float* Wih1f = (const float*)d_in[11];
    const float* Whh1f = (const float*)d_in[12];
    const float* bih1f = (const float*)d_in[13];
    const float* bhh1f = (const float*)d_in[14];
    const float* Wih1b = (const float*)d_in[15];
    const float* Whh1b = (const float*)d_in[16];
    const float* bih1b = (const float*)d_in[17];
    const float* bhh1b = (const float*)d_in[18];
    const float* fc1W  = (const float*)d_in[19];
    const float* fc1b  = (const float*)d_in[20];
    const float* fc2W  = (const float*)d_in[21];
    const float* fc2b  = (const float*)d_in[22];
    float* out = (float*)d_out;

    // ws: gx dbuf fp16 (2x15.73MB) | out0 fp16 (41.94MB) | small | fp16 tables
    char* p = (char*)d_ws;
    const size_t gxB = (size_t)2 * BB * TC * GG * sizeof(__half);
    __half* gxb0  = (__half*)p;  p += gxB;
    __half* gxb1  = (__half*)p;  p += gxB;
    __half* out0  = (__half*)p;  p += (size_t)BB * TT * 2 * HH * sizeof(__half);
    float*  hcar  = (float*)p;   p += (size_t)2 * BB * HH * sizeof(float);
    float*  hlast = (float*)p;   p += (size_t)4 * BB * HH * sizeof(float);
    float*  sumb  = (float*)p;   p += (size_t)BB * 2 * HH * sizeof(float);
    float*  maxb  = (float*)p;   p += (size_t)BB * 2 * HH * sizeof(float);
    __half*    emb16 = (__half*)p;    p += (size_t)50000 * EE * sizeof(__half);
    h2_t*      Wt16  = (h2_t*)p;      p += (size_t)(NW_L0 + NW_L1) * sizeof(h2_t);
    _Float16*  Whh16 = (_Float16*)p;
    __half* gxb[2] = { gxb0, gxb1 };

    const int NG = BB * 2 * 2;   // 2048 gemm blocks
    const int NS = 256;          // 1024 chains / 4 waves per block

    // ---- precompute fp16 tables ----
    {
        const int total = NE_EMB + NW_L0 + NW_L1 + NW_HH;
        prep_kernel<<<(total + 255) / 256, 256, 0, stream>>>(
            emb, Wih0f, Wih0b, Wih1f, Wih1b, Whh0f, Whh0b, Whh1f, Whh1b,
            emb16, Wt16, Whh16);
    }

    // ---- layer 0 ----
    fused_kernel<EE, true><<<NG, 256, 0, stream>>>(0, 0, 0,
        text, emb16, nullptr, Wt16, bih0f, bih0b,
        gxb[0], gxb[0], Whh16, bhh0f, bhh0b,
        lens, out0, hcar, hlast, sumb, maxb);
    for (int ci = 1; ci < NC; ++ci)
        fused_kernel<EE, true><<<NS + NG, 256, 0, stream>>>(ci, ci - 1, NS,
            text, emb16, nullptr, Wt16, bih0f, bih0b,
            gxb[ci & 1], gxb[(ci - 1) & 1], Whh16, bhh0f, bhh0b,
            lens, out0, hcar, hlast, sumb, maxb);
    fused_kernel<EE, true><<<NS, 256, 0, stream>>>(0, NC - 1, NS,
        text, emb16, nullptr, Wt16, bih0f, bih0b,
        gxb[0], gxb[(NC - 1) & 1], Whh16, bhh0f, bhh0b,
        lens, out0, hcar, hlast, sumb, maxb);

    // ---- layer 1 ----
    fused_kernel<2*HH, false><<<NG, 256, 0, stream>>>(0, 0, 0,
        text, emb16, out0, Wt16 + NW_L0, bih1f, bih1b,
        gxb[0], gxb[0], Whh16 + 9600, bhh1f, bhh1b,
        lens, out0, hcar, hlast, sumb, maxb);
    for (int ci = 1; ci < NC; ++ci)
        fused_kernel<2*HH, false><<<NS + NG, 256, 0, stream>>>(ci, ci - 1, NS,
            text, emb16, out0, Wt16 + NW_L0, bih1f, bih1b,
            gxb[ci & 1], gxb[(ci - 1) & 1], Whh16 + 9600, bhh1f, bhh1b,
            lens, out0, hcar, hlast, sumb, maxb);
    fused_kernel<2*HH, false><<<NS, 256, 0, stream>>>(0, NC - 1, NS,
        text, emb16, out0, Wt16 + NW_L0, bih1f, bih1b,
        gxb[0], gxb[(NC - 1) & 1], Whh16 + 9600, bhh1f, bhh1b,
        lens, out0, hcar, hlast, sumb, maxb);

    // ---- head ----
    fc_kernel<<<BB, 128, 0, stream>>>(hlast, sumb, maxb, lens,
        fc1W, fc1b, fc2W, fc2b, out);
}

// Round 4
// 656.872 us; speedup vs baseline: 1.1078x; 1.0323x over previous
//
#include <hip/hip_runtime.h>
#include <hip/hip_fp16.h>

#define BB 512
#define TT 512
#define EE 100
#define HH 40
#define GG 120   // 3*HH
#define TC 64    // timesteps per chunk
#define NC 8     // chunks
#define X1S 96   // layer-1 input row stride (80 valid + 16 pad, 3 k-steps of 32)

typedef _Float16 h2_t __attribute__((ext_vector_type(2)));
typedef _Float16 h8_t __attribute__((ext_vector_type(8)));
typedef float    f4_t __attribute__((ext_vector_type(4)));

__device__ __forceinline__ float fdot2_(h2_t a, h2_t b, float c) {
    return __builtin_amdgcn_fdot2(a, b, c, false);
}
__device__ __forceinline__ h2_t pack2_(float x, float y) {
    h2_t r; r[0] = (_Float16)x; r[1] = (_Float16)y; return r;
}
__device__ __forceinline__ float sigmoid_(float x) {
    return 1.0f / (1.0f + __expf(-x));
}
__device__ __forceinline__ float tanhfast_(float x) {
    float e = __expf(2.0f * x);
    return 1.0f - 2.0f / (e + 1.0f);
}

// Round-13 = round-12 resubmit (container infra failure, no data) + hardening.
// Model recap: r2 falsified "staging cost" (FETCH halved, cvts gone, time
// unchanged 42us). Remaining structural cost of dot2 GEMM: 32B LDS per 64
// FLOP -> ~3200 wave ds_read_b128 x ~12cy per CU per dispatch on the single
// shared LDS pipe + 1600cy VALU issue per wave at ~1.3 waves/SIMD effective.
// Fix = MFMA datapath:
//  - one block per (b,chunk,dir); wave w: rows w*16..+15, 8 col-frags x KS
//    k-steps of mfma_f32_16x16x32_f16 (KS=4 K=100->128pad; KS=3 K=80->96pad).
//  - A gathered DIRECTLY from global into fragment regs (lane: row=l&15,
//    k-chunk=(l>>4)*8) -- X never touches LDS. emb16 padded to 128 halfs.
//  - W pre-transposed by prep into the exact B-fragment LDS image; staging is
//    a raw float4 memcpy; B reads are contiguous ds_read_b128 (no conflicts).
// Hardening this round: prep zeroes out0's pad columns (halfs 80..95 of every
// row) so layer-1 MFMA correctness does not depend on workspace poison being
// finite (NaN poison x zero-W would otherwise produce NaN in valid gx rows).
// Layouts (verified, m89): A[m=l%16][k=(l>>4)*8+i], B[k=(l>>4)*8+i][n=l%16],
// D[m=(l>>4)*4+reg][n=l%16]. Scan path unchanged (hidden under GEMM so far).
template<int K, bool GATHER>
__global__ __launch_bounds__(256, 4) void fused_kernel(
    const int cg, const int cs, const int nScan,
    const int* __restrict__ text, const __half* __restrict__ emb16,
    const __half* __restrict__ Xh,
    const _Float16* __restrict__ Wt,
    const float* __restrict__ bf, const float* __restrict__ bb,
    __half* __restrict__ gxW, const __half* __restrict__ gxR,
    const _Float16* __restrict__ WhhL,
    const float* __restrict__ bhhF, const float* __restrict__ bhhB,
    const int* __restrict__ lens,
    __half* __restrict__ out0,
    float* __restrict__ hcar, float* __restrict__ hlast,
    float* __restrict__ sumb, float* __restrict__ maxb)
{
    constexpr int KS = (K == 100) ? 4 : 3;       // k-steps of 32
    __shared__ __align__(16) _Float16 Wlds[KS * 8 * 64 * 8];
    __shared__ __align__(16) _Float16 hsh[4][48];
    const int tid = threadIdx.x;

    if ((int)blockIdx.x < nScan) {
        // ============ scan: one wave = one (batch,dir) chain ============
        __builtin_amdgcn_s_setprio(3);
        const int wave = tid >> 6, j = tid & 63;
        if (j >= HH) return;
        const int chain = blockIdx.x * 4 + wave;   // 0..1023
        const int dir = chain >> 9;
        const int b   = chain & (BB - 1);
        const float* bhh = dir ? bhhB : bhhF;

        // Whh rows {j,40+j,80+j} as fp16 in 15 NAMED h8 registers.
        h8_t R0,R1,R2,R3,R4, Z0,Z1,Z2,Z3,Z4, N0,N1,N2,N3,N4;
        {
            const _Float16* wr = WhhL + (size_t)dir * 4800;
            const h8_t* pr = (const h8_t*)(wr + (size_t)j * 40);
            const h8_t* pz = (const h8_t*)(wr + (size_t)(40 + j) * 40);
            const h8_t* pn = (const h8_t*)(wr + (size_t)(80 + j) * 40);
            R0=pr[0]; R1=pr[1]; R2=pr[2]; R3=pr[3]; R4=pr[4];
            Z0=pz[0]; Z1=pz[1]; Z2=pz[2]; Z3=pz[3]; Z4=pz[4];
            N0=pn[0]; N1=pn[1]; N2=pn[2]; N3=pn[3]; N4=pn[4];
        }
        const float br = bhh[j], bz = bhh[HH + j], bn = bhh[2*HH + j];
        const int len = lens[b];
        const int chunk = dir ? (NC - 1 - cs) : cs;
        const int tbase = chunk * TC;

        // executed step range: all executed steps have t < len
        int sBeg, sEnd;
        if (dir == 0) { sBeg = 0; sEnd = min(TC, max(0, len - tbase)); }
        else          { sBeg = max(0, tbase + TC - len); sEnd = TC; }

        float h = (cs == 0) ? 0.0f : hcar[(size_t)(dir * BB + b) * HH + j];
        hsh[wave][j] = (_Float16)h;
        float psum = 0.0f, pmax = -3.4e38f;
        const size_t gxRow = ((size_t)dir * BB + b) * TC;
        const float4* h4 = (const float4*)hsh[wave];

        struct G3 { __half r, z, n; };
        auto ldg3 = [&](int sc) -> G3 {
            const int tl = dir ? (TC - 1 - sc) : sc;
            const __half* gp = gxR + (gxRow + tl) * GG;
            G3 g; g.r = gp[j]; g.z = gp[HH + j]; g.n = gp[2*HH + j];
            return g;
        };
#define SL(V,i) __builtin_shufflevector(V, V, 2*(i), 2*(i)+1)
#define DOTQ(Rq,Zq,Nq,U) \
        r0 = fdot2_(SL(Rq,0), U.hh[0], r0); \
        z0 = fdot2_(SL(Zq,0), U.hh[0], z0); \
        n0 = fdot2_(SL(Nq,0), U.hh[0], n0); \
        r1 = fdot2_(SL(Rq,1), U.hh[1], r1); \
        z1 = fdot2_(SL(Zq,1), U.hh[1], z1); \
        n1 = fdot2_(SL(Nq,1), U.hh[1], n1); \
        r0 = fdot2_(SL(Rq,2), U.hh[2], r0); \
        z0 = fdot2_(SL(Zq,2), U.hh[2], z0); \
        n0 = fdot2_(SL(Nq,2), U.hh[2], n0); \
        r1 = fdot2_(SL(Rq,3), U.hh[3], r1); \
        z1 = fdot2_(SL(Zq,3), U.hh[3], z1); \
        n1 = fdot2_(SL(Nq,3), U.hh[3], n1);

        constexpr int PF = 4;   // prefetch depth
        auto step = [&](int s, G3& g, bool pf) {
            G3 nx;
            if (pf) nx = ldg3(min(s + PF, sEnd - 1));  // clamped: always in-slab
            const int tloc = dir ? (TC - 1 - s) : s;
            float r0 = br, r1 = 0.f, z0 = bz, z1 = 0.f, n0 = bn, n1 = 0.f;
            union { float4 f; h2_t hh[4]; } u0, u1, u2, u3, u4;
            u0.f = h4[0]; u1.f = h4[1]; u2.f = h4[2]; u3.f = h4[3]; u4.f = h4[4];
            DOTQ(R0,Z0,N0,u0)
            DOTQ(R1,Z1,N1,u1)
            DOTQ(R2,Z2,N2,u2)
            DOTQ(R3,Z3,N3,u3)
            DOTQ(R4,Z4,N4,u4)
            const float rr = sigmoid_(__half2float(g.r) + r0 + r1);
            const float zz = sigmoid_(__half2float(g.z) + z0 + z1);
            const float nn = tanhfast_(__half2float(g.n) + rr * (n0 + n1));
            const float hn = (1.0f - zz) * nn + zz * h;
            h = hn;                        // all executed steps are valid
            hsh[wave][j] = (_Float16)h;    // broadcast for next step
            if (GATHER) {  // layer 0: materialize out0 fp16 (valid t only)
                const int t = tbase + tloc;
                out0[((size_t)b * TT + t) * X1S + dir*HH + j] = __float2half(hn);
            } else {       // layer 1: fused pooling (valid t only)
                psum += hn;
                pmax = fmaxf(pmax, hn);
            }
            if (pf) g = nx;
        };

        G3 q0 = {}, q1 = {}, q2 = {}, q3 = {};
        if (sBeg < sEnd) {
            q0 = ldg3(sBeg);
            q1 = ldg3(min(sBeg + 1, sEnd - 1));
            q2 = ldg3(min(sBeg + 2, sEnd - 1));
            q3 = ldg3(min(sBeg + 3, sEnd - 1));
        }
        int s = sBeg;
        for (; s + PF <= sEnd; s += PF) {
            step(s + 0, q0, true);
            step(s + 1, q1, true);
            step(s + 2, q2, true);
            step(s + 3, q3, true);
        }
        if (s     < sEnd) step(s,     q0, false);
        if (s + 1 < sEnd) step(s + 1, q1, false);
        if (s + 2 < sEnd) step(s + 2, q2, false);

        hcar[(size_t)(dir * BB + b) * HH + j] = h;
        const int layer = GATHER ? 0 : 1;
        if (cs == NC - 1)
            hlast[((size_t)(layer * 2 + dir) * BB + b) * HH + j] = h;
        if (!GATHER) {
            const size_t pi = (size_t)b * (2*HH) + dir*HH + j;
            if (cs == 0) { sumb[pi] = psum;  maxb[pi] = pmax; }
            else         { sumb[pi] += psum; maxb[pi] = fmaxf(maxb[pi], pmax); }
        }
        return;
    }

    // ================= gemm (MFMA f16), prio 0 =================
    __builtin_amdgcn_s_setprio(0);
    const int gid = blockIdx.x - nScan;
    const int b   = gid & (BB - 1);
    const int dir = gid >> 9;
    const int chunk = dir ? (NC - 1 - cg) : cg;
    const int tbase = chunk * TC;
    if (tbase >= lens[b]) return;   // tile fully past len: gx never read
    const float* bias = dir ? bb : bf;

    // stage W: raw float4 memcpy of pre-built B-fragment image (KS*8*64*16 B)
    {
        const float4* src = (const float4*)(Wt + (size_t)dir * (KS * 8 * 64 * 8));
        float4* dst = (float4*)Wlds;
        for (int i = tid; i < KS * 8 * 64; i += 256) dst[i] = src[i];
    }

    // A gather: lane l -> row = l&15 of wave's 16-row stripe, k-chunk (l>>4)*8
    const int w = tid >> 6, l = tid & 63;
    const int row = l & 15, kq = l >> 4;
    const int t0 = tbase + w * 16 + row;
    h8_t A[4];
    if (GATHER) {
        const int tok = text[b * TT + t0];
        const _Float16* ap = (const _Float16*)emb16 + (size_t)tok * 128 + kq * 8;
        #pragma unroll
        for (int ks = 0; ks < KS; ++ks) A[ks] = *(const h8_t*)(ap + ks * 32);
    } else {
        const _Float16* ap = (const _Float16*)Xh + ((size_t)b * TT + t0) * X1S + kq * 8;
        #pragma unroll
        for (int ks = 0; ks < KS; ++ks) A[ks] = *(const h8_t*)(ap + ks * 32);
    }
    __syncthreads();

    f4_t acc[8] = {};
    #pragma unroll
    for (int ks = 0; ks < KS; ++ks)
        #pragma unroll
        for (int f = 0; f < 8; ++f) {
            const h8_t Bf = *(const h8_t*)(Wlds + ((size_t)(ks * 8 + f) * 64 + l) * 8);
            acc[f] = __builtin_amdgcn_mfma_f32_16x16x32_f16(A[ks], Bf, acc[f], 0, 0, 0);
        }

    // epilogue: D[m=(l>>4)*4+reg][n=l&15]; per-element fp16 stores
    const size_t rowB = ((size_t)dir * BB + b) * TC;
    const int gb = l & 15, rq = l >> 4;
    #pragma unroll
    for (int f = 0; f < 8; ++f) {
        const int gate = f * 16 + gb;
        if (gate < GG) {
            const float bv = bias[gate];
            #pragma unroll
            for (int r = 0; r < 4; ++r) {
                const int tloc = w * 16 + rq * 4 + r;
                gxW[(rowB + tloc) * GG + gate] = __float2half(acc[f][r] + bv);
            }
        }
    }
}

// Precompute fp16 tables:
//  emb16 [50000][128] zero-padded; Wt16 = exact B-fragment images:
//  L0 [dir][ks<4][f<8][l<64][i<8], L1 [dir][ks<3][f<8][l<64][i<8];
//  Whh16 fp16 row-major [lay*2+dir][120][40]; plus zero out0 pad columns.
#define NE2 (50000 * 64)        // h2 units of padded emb16
#define NW0 (2*4*8*64)          // 4096 h8 units
#define NW1 (2*3*8*64)          // 3072 h8 units
#define NHH (4*120*20)          // 9600 h2 units
#define NP0 (BB*TT*8)           // h2 units of out0 pad (16 halfs/row)
__global__ __launch_bounds__(256) void prep_kernel(
    const float* __restrict__ emb,
    const float* __restrict__ Wih0f, const float* __restrict__ Wih0b,
    const float* __restrict__ Wih1f, const float* __restrict__ Wih1b,
    const float* __restrict__ Whh0f, const float* __restrict__ Whh0b,
    const float* __restrict__ Whh1f, const float* __restrict__ Whh1b,
    __half* __restrict__ emb16, _Float16* __restrict__ Wt16,
    _Float16* __restrict__ Whh16, __half* __restrict__ out0)
{
    const int gid = blockIdx.x * 256 + threadIdx.x;
    if (gid < NE2) {
        const int v = gid >> 6, q2 = gid & 63;
        const int k0 = q2 * 2;
        float x0 = 0.f, x1 = 0.f;
        if (k0 < EE) { x0 = emb[(size_t)v * EE + k0]; x1 = emb[(size_t)v * EE + k0 + 1]; }
        ((h2_t*)emb16)[(size_t)v * 64 + q2] = pack2_(x0, x1);
        return;
    }
    int e = gid - NE2;
    if (e < NP0) {              // zero out0 pad columns (halfs 80..95 per row)
        const int row = e >> 3, q = e & 7;
        ((h2_t*)out0)[(size_t)row * 48 + 40 + q] = pack2_(0.f, 0.f);
        return;
    }
    e -= NP0;
    if (e < NW0) {              // layer0 B-fragments, K=100 (pad 128)
        const int l = e & 63, f = (e >> 6) & 7, ks = (e >> 9) & 3, dir = e >> 11;
        const float* W = dir ? Wih0b : Wih0f;
        const int col = f * 16 + (l & 15);
        const int kb  = ks * 32 + (l >> 4) * 8;
        _Float16* dst = Wt16 + (size_t)e * 8;
        #pragma unroll
        for (int i = 0; i < 8; ++i) {
            const int k = kb + i;
            dst[i] = (_Float16)((col < GG && k < EE) ? W[(size_t)col * EE + k] : 0.f);
        }
        return;
    }
    e -= NW0;
    if (e < NW1) {              // layer1 B-fragments, K=80 (pad 96)
        const int l = e & 63, f = (e >> 6) & 7;
        const int t = e >> 9;               // 0..5 = dir*3 + ks
        const int ks = t % 3, dir = t / 3;
        const float* W = dir ? Wih1b : Wih1f;
        const int col = f * 16 + (l & 15);
        const int kb  = ks * 32 + (l >> 4) * 8;
        _Float16* dst = Wt16 + (size_t)(NW0 + e) * 8;
        #pragma unroll
        for (int i = 0; i < 8; ++i) {
            const int k = kb + i;
            dst[i] = (_Float16)((col < GG && k < 2*HH) ? W[(size_t)col * (2*HH) + k] : 0.f);
        }
        return;
    }
    e -= NW1;
    if (e < NHH) {              // Whh fp16, 4 x [120][40]
        const int ld = e / 2400, rem = e - ld * 2400;
        const int row2 = rem / 20, kk = rem - row2 * 20;
        const float* W = (ld == 0) ? Whh0f : (ld == 1) ? Whh0b
                       : (ld == 2) ? Whh1f : Whh1b;
        ((h2_t*)Whh16)[e] = pack2_(W[row2*HH + 2*kk], W[row2*HH + 2*kk + 1]);
    }
}

// pool_cat = [hb1, hf1, hb0, hf0, avg(80), max(80)] -> fc1(128) -> lrelu -> fc2(1)
__global__ __launch_bounds__(128) void fc_kernel(
    const float* __restrict__ hlast, const float* __restrict__ sumb,
    const float* __restrict__ maxb, const int* __restrict__ lens,
    const float* __restrict__ fc1W, const float* __restrict__ fc1b,
    const float* __restrict__ fc2W, const float* __restrict__ fc2b,
    float* __restrict__ out)
{
    __shared__ float pool[8 * HH];
    __shared__ float red[128];
    const int b = blockIdx.x, tid = threadIdx.x;
    if (tid < HH) {
        pool[tid]        = hlast[(size_t)(3*BB + b) * HH + tid]; // hb1
        pool[HH + tid]   = hlast[(size_t)(2*BB + b) * HH + tid]; // hf1
        pool[2*HH + tid] = hlast[(size_t)(1*BB + b) * HH + tid]; // hb0
        pool[3*HH + tid] = hlast[(size_t)(0*BB + b) * HH + tid]; // hf0
    }
    const float invLen = 1.0f / (float)lens[b];
    if (tid < 2*HH) {
        pool[4*HH + tid] = sumb[(size_t)b * 2*HH + tid] * invLen;
        pool[6*HH + tid] = maxb[(size_t)b * 2*HH + tid];
    }
    __syncthreads();
    float acc = fc1b[tid];
    for (int k = 0; k < 8*HH; ++k)
        acc = fmaf(pool[k], fc1W[(size_t)tid * (8*HH) + k], acc);
    float v = (acc >= 0.0f) ? acc : 0.01f * acc;
    red[tid] = v * fc2W[tid];
    __syncthreads();
    for (int s = 64; s > 0; s >>= 1) {
        if (tid < s) red[tid] += red[tid + s];
        __syncthreads();
    }
    if (tid == 0) out[b] = red[0] + fc2b[0];
}

extern "C" void kernel_launch(void* const* d_in, const int* in_sizes, int n_in,
                              void* d_out, int out_size, void* d_ws, size_t ws_size,
                              hipStream_t stream) {
    const int*   text  = (const int*)d_in[0];
    const int*   lens  = (const int*)d_in[1];
    const float* emb   = (const float*)d_in[2];
    const float* Wih0f = (const float*)d_in[3];
    const float* Whh0f = (const float*)d_in[4];
    const float* bih0f = (const float*)d_in[5];
    const float* bhh0f = (const float*)d_in[6];
    const float* Wih0b = (const float*)d_in[7];
    const float* Whh0b = (const float*)d_in[8];
    const float* bih0b = (const float*)d_in[9];
    const float* bhh0b = (const float*)d_in[10];
    const float* Wih1f = (const float*)d_in[11];
    const float* Whh1f = (const float*)d_in[12];
    const float* bih1f = (const float*)d_in[13];
    const float* bhh1f = (const float*)d_in[14];
    const float* Wih1b = (const float*)d_in[15];
    const float* Whh1b = (const float*)d_in[16];
    const float* bih1b = (const float*)d_in[17];
    const float* bhh1b = (const float*)d_in[18];
    const float* fc1W  = (const float*)d_in[19];
    const float* fc1b  = (const float*)d_in[20];
    const float* fc2W  = (const float*)d_in[21];
    const float* fc2b  = (const float*)d_in[22];
    float* out = (float*)d_out;

    // ws: gx dbuf fp16 | out0 fp16 (stride 96) | small | fp16 tables
    char* p = (char*)d_ws;
    const size_t gxB = (size_t)2 * BB * TC * GG * sizeof(__half);
    __half* gxb0  = (__half*)p;  p += gxB;
    __half* gxb1  = (__half*)p;  p += gxB;
    __half* out0  = (__half*)p;  p += (size_t)BB * TT * X1S * sizeof(__half);
    float*  hcar  = (float*)p;   p += (size_t)2 * BB * HH * sizeof(float);
    float*  hlast = (float*)p;   p += (size_t)4 * BB * HH * sizeof(float);
    float*  sumb  = (float*)p;   p += (size_t)BB * 2 * HH * sizeof(float);
    float*  maxb  = (float*)p;   p += (size_t)BB * 2 * HH * sizeof(float);
    __half*    emb16 = (__half*)p;    p += (size_t)50000 * 128 * sizeof(__half);
    _Float16*  Wt16  = (_Float16*)p;  p += (size_t)(NW0 + NW1) * 8 * sizeof(_Float16);
    _Float16*  Whh16 = (_Float16*)p;
    __half* gxb[2] = { gxb0, gxb1 };

    const int NG = BB * 2;       // 1024 gemm blocks (b, dir)
    const int NS = 256;          // 1024 chains / 4 waves per block

    // ---- precompute fp16 tables + out0 pad zeroing ----
    {
        const int total = NE2 + NP0 + NW0 + NW1 + NHH;
        prep_kernel<<<(total + 255) / 256, 256, 0, stream>>>(
            emb, Wih0f, Wih0b, Wih1f, Wih1b, Whh0f, Whh0b, Whh1f, Whh1b,
            emb16, Wt16, Whh16, out0);
    }

    // ---- layer 0 ----
    fused_kernel<EE, true><<<NG, 256, 0, stream>>>(0, 0, 0,
        text, emb16, nullptr, Wt16, bih0f, bih0b,
        gxb[0], gxb[0], Whh16, bhh0f, bhh0b,
        lens, out0, hcar, hlast, sumb, maxb);
    for (int ci = 1; ci < NC; ++ci)
        fused_kernel<EE, true><<<NS + NG, 256, 0, stream>>>(ci, ci - 1, NS,
            text, emb16, nullptr, Wt16, bih0f, bih0b,
            gxb[ci & 1], gxb[(ci - 1) & 1], Whh16, bhh0f, bhh0b,
            lens, out0, hcar, hlast, sumb, maxb);
    fused_kernel<EE, true><<<NS, 256, 0, stream>>>(0, NC - 1, NS,
        text, emb16, nullptr, Wt16, bih0f, bih0b,
        gxb[0], gxb[(NC - 1) & 1], Whh16, bhh0f, bhh0b,
        lens, out0, hcar, hlast, sumb, maxb);

    // ---- layer 1 ----
    fused_kernel<2*HH, false><<<NG, 256, 0, stream>>>(0, 0, 0,
        text, emb16, out0, Wt16 + (size_t)NW0 * 8, bih1f, bih1b,
        gxb[0], gxb[0], Whh16 + 9600, bhh1f, bhh1b,
        lens, out0, hcar, hlast, sumb, maxb);
    for (int ci = 1; ci < NC; ++ci)
        fused_kernel<2*HH, false><<<NS + NG, 256, 0, stream>>>(ci, ci - 1, NS,
            text, emb16, out0, Wt16 + (size_t)NW0 * 8, bih1f, bih1b,
            gxb[ci & 1], gxb[(ci - 1) & 1], Whh16 + 9600, bhh1f, bhh1b,
            lens, out0, hcar, hlast, sumb, maxb);
    fused_kernel<2*HH, false><<<NS, 256, 0, stream>>>(0, NC - 1, NS,
        text, emb16, out0, Wt16 + (size_t)NW0 * 8, bih1f, bih1b,
        gxb[0], gxb[(NC - 1) & 1], Whh16 + 9600, bhh1f, bhh1b,
        lens, out0, hcar, hlast, sumb, maxb);

    // ---- head ----
    fc_kernel<<<BB, 128, 0, stream>>>(hlast, sumb, maxb, lens,
        fc1W, fc1b, fc2W, fc2b, out);
}

// Round 5
// 572.273 us; speedup vs baseline: 1.2716x; 1.1478x over previous
//
#include <hip/hip_runtime.h>
#include <hip/hip_fp16.h>

#define BB 512
#define TT 512
#define EE 100
#define HH 40
#define GG 120   // 3*HH
#define TC 64    // timesteps per chunk
#define NC 8     // chunks
#define X1S 96   // layer-1 input row stride (80 valid + 16 pad, 3 k-steps of 32)

typedef _Float16 h2_t __attribute__((ext_vector_type(2)));
typedef _Float16 h8_t __attribute__((ext_vector_type(8)));
typedef float    f4_t __attribute__((ext_vector_type(4)));

__device__ __forceinline__ float fdot2_(h2_t a, h2_t b, float c) {
    return __builtin_amdgcn_fdot2(a, b, c, false);
}
__device__ __forceinline__ h2_t pack2_(float x, float y) {
    h2_t r; r[0] = (_Float16)x; r[1] = (_Float16)y; return r;
}
__device__ __forceinline__ float sigmoid_(float x) {
    return __builtin_amdgcn_rcpf(1.0f + __expf(-x));
}
__device__ __forceinline__ float tanhfast_(float x) {
    return 1.0f - 2.0f * __builtin_amdgcn_rcpf(__expf(2.0f * x) + 1.0f);
}

// Round-14 model: r4 proved the GEMM path is cheap (MFMA) yet mixed dispatches
// stayed 42.4us => the SCAN is the pole: total ~= 16 scan-chunks x 42us, i.e.
// 1575cy/step vs a ~450cy dep-chain model. Two culprits identified:
//  (a) VGPR_Count=64 in r2 AND r4: the allocator NEVER kept the 15 named h8
//      Whh registers resident -- it rematerializes the loop-invariant global
//      loads INSIDE the step loop (15 x ~200cy L2 latency per step, vmcnt on
//      the critical path). Fix: asm keep-alive ("+v" on all 15 h8 values)
//      makes remat illegal; __launch_bounds__(256,2) raises the VGPR cap.
//  (b) GEMM blocks' LDS staging (2048 ds_write_b128/block, 4 blocks/CU)
//      contends with the scan's h-broadcast on the single per-CU LDS pipe.
//      Fix: GEMM reads B-fragments straight from L2-resident Wt16 (32KB),
//      no LDS, no __syncthreads -- the LDS pipe belongs to the scan.
// Plus rcp-based sigmoid/tanh (drops divide refinement from the serial chain).
// Markers for next profile: VGPR ~110-130 (residency took), LDS_Block ~512.
template<int K, bool GATHER>
__global__ __launch_bounds__(256, 2) void fused_kernel(
    const int cg, const int cs, const int nScan,
    const int* __restrict__ text, const __half* __restrict__ emb16,
    const __half* __restrict__ Xh,
    const _Float16* __restrict__ Wt,
    const float* __restrict__ bf, const float* __restrict__ bb,
    __half* __restrict__ gxW, const __half* __restrict__ gxR,
    const _Float16* __restrict__ WhhL,
    const float* __restrict__ bhhF, const float* __restrict__ bhhB,
    const int* __restrict__ lens,
    __half* __restrict__ out0,
    float* __restrict__ hcar, float* __restrict__ hlast,
    float* __restrict__ sumb, float* __restrict__ maxb)
{
    constexpr int KS = (K == 100) ? 4 : 3;       // k-steps of 32
    __shared__ __align__(16) _Float16 hsh[4][48];
    const int tid = threadIdx.x;

    if ((int)blockIdx.x < nScan) {
        // ============ scan: one wave = one (batch,dir) chain ============
        __builtin_amdgcn_s_setprio(3);
        const int wave = tid >> 6, j = tid & 63;
        if (j >= HH) return;
        const int chain = blockIdx.x * 4 + wave;   // 0..1023
        const int dir = chain >> 9;
        const int b   = chain & (BB - 1);
        const float* bhh = dir ? bhhB : bhhF;

        // Whh rows {j,40+j,80+j} as fp16 in 15 h8 registers, FORCED resident:
        // the asm below marks them modified so the allocator cannot remat the
        // loads inside the loop (r2/r4 showed it otherwise reloads per step).
        h8_t R0,R1,R2,R3,R4, Z0,Z1,Z2,Z3,Z4, N0,N1,N2,N3,N4;
        {
            const _Float16* wr = WhhL + (size_t)dir * 4800;
            const h8_t* pr = (const h8_t*)(wr + (size_t)j * 40);
            const h8_t* pz = (const h8_t*)(wr + (size_t)(40 + j) * 40);
            const h8_t* pn = (const h8_t*)(wr + (size_t)(80 + j) * 40);
            R0=pr[0]; R1=pr[1]; R2=pr[2]; R3=pr[3]; R4=pr[4];
            Z0=pz[0]; Z1=pz[1]; Z2=pz[2]; Z3=pz[3]; Z4=pz[4];
            N0=pn[0]; N1=pn[1]; N2=pn[2]; N3=pn[3]; N4=pn[4];
        }
        asm volatile("" : "+v"(R0),"+v"(R1),"+v"(R2),"+v"(R3),"+v"(R4),
                          "+v"(Z0),"+v"(Z1),"+v"(Z2),"+v"(Z3),"+v"(Z4),
                          "+v"(N0),"+v"(N1),"+v"(N2),"+v"(N3),"+v"(N4));
        const float br = bhh[j], bz = bhh[HH + j], bn = bhh[2*HH + j];
        const int len = lens[b];
        const int chunk = dir ? (NC - 1 - cs) : cs;
        const int tbase = chunk * TC;

        // executed step range: all executed steps have t < len
        int sBeg, sEnd;
        if (dir == 0) { sBeg = 0; sEnd = min(TC, max(0, len - tbase)); }
        else          { sBeg = max(0, tbase + TC - len); sEnd = TC; }

        float h = (cs == 0) ? 0.0f : hcar[(size_t)(dir * BB + b) * HH + j];
        hsh[wave][j] = (_Float16)h;
        float psum = 0.0f, pmax = -3.4e38f;
        const size_t gxRow = ((size_t)dir * BB + b) * TC;
        const float4* h4 = (const float4*)hsh[wave];

        struct G3 { __half r, z, n; };
        auto ldg3 = [&](int sc) -> G3 {
            const int tl = dir ? (TC - 1 - sc) : sc;
            const __half* gp = gxR + (gxRow + tl) * GG;
            G3 g; g.r = gp[j]; g.z = gp[HH + j]; g.n = gp[2*HH + j];
            return g;
        };
#define SL(V,i) __builtin_shufflevector(V, V, 2*(i), 2*(i)+1)
#define DOTQ(Rq,Zq,Nq,U) \
        r0 = fdot2_(SL(Rq,0), U.hh[0], r0); \
        z0 = fdot2_(SL(Zq,0), U.hh[0], z0); \
        n0 = fdot2_(SL(Nq,0), U.hh[0], n0); \
        r1 = fdot2_(SL(Rq,1), U.hh[1], r1); \
        z1 = fdot2_(SL(Zq,1), U.hh[1], z1); \
        n1 = fdot2_(SL(Nq,1), U.hh[1], n1); \
        r0 = fdot2_(SL(Rq,2), U.hh[2], r0); \
        z0 = fdot2_(SL(Zq,2), U.hh[2], z0); \
        n0 = fdot2_(SL(Nq,2), U.hh[2], n0); \
        r1 = fdot2_(SL(Rq,3), U.hh[3], r1); \
        z1 = fdot2_(SL(Zq,3), U.hh[3], z1); \
        n1 = fdot2_(SL(Nq,3), U.hh[3], n1);

        constexpr int PF = 4;   // prefetch depth
        auto step = [&](int s, G3& g, bool pf) {
            G3 nx;
            if (pf) nx = ldg3(min(s + PF, sEnd - 1));  // clamped: always in-slab
            const int tloc = dir ? (TC - 1 - s) : s;
            float r0 = br, r1 = 0.f, z0 = bz, z1 = 0.f, n0 = bn, n1 = 0.f;
            union { float4 f; h2_t hh[4]; } u0, u1, u2, u3, u4;
            u0.f = h4[0]; u1.f = h4[1]; u2.f = h4[2]; u3.f = h4[3]; u4.f = h4[4];
            DOTQ(R0,Z0,N0,u0)
            DOTQ(R1,Z1,N1,u1)
            DOTQ(R2,Z2,N2,u2)
            DOTQ(R3,Z3,N3,u3)
            DOTQ(R4,Z4,N4,u4)
            const float rr = sigmoid_(__half2float(g.r) + r0 + r1);
            const float zz = sigmoid_(__half2float(g.z) + z0 + z1);
            const float nn = tanhfast_(__half2float(g.n) + rr * (n0 + n1));
            const float hn = (1.0f - zz) * nn + zz * h;
            h = hn;                        // all executed steps are valid
            hsh[wave][j] = (_Float16)h;    // broadcast for next step
            if (GATHER) {  // layer 0: materialize out0 fp16 (valid t only)
                const int t = tbase + tloc;
                out0[((size_t)b * TT + t) * X1S + dir*HH + j] = __float2half(hn);
            } else {       // layer 1: fused pooling (valid t only)
                psum += hn;
                pmax = fmaxf(pmax, hn);
            }
            if (pf) g = nx;
        };

        G3 q0 = {}, q1 = {}, q2 = {}, q3 = {};
        if (sBeg < sEnd) {
            q0 = ldg3(sBeg);
            q1 = ldg3(min(sBeg + 1, sEnd - 1));
            q2 = ldg3(min(sBeg + 2, sEnd - 1));
            q3 = ldg3(min(sBeg + 3, sEnd - 1));
        }
        int s = sBeg;
        for (; s + PF <= sEnd; s += PF) {
            step(s + 0, q0, true);
            step(s + 1, q1, true);
            step(s + 2, q2, true);
            step(s + 3, q3, true);
        }
        if (s     < sEnd) step(s,     q0, false);
        if (s + 1 < sEnd) step(s + 1, q1, false);
        if (s + 2 < sEnd) step(s + 2, q2, false);

        hcar[(size_t)(dir * BB + b) * HH + j] = h;
        const int layer = GATHER ? 0 : 1;
        if (cs == NC - 1)
            hlast[((size_t)(layer * 2 + dir) * BB + b) * HH + j] = h;
        if (!GATHER) {
            const size_t pi = (size_t)b * (2*HH) + dir*HH + j;
            if (cs == 0) { sumb[pi] = psum;  maxb[pi] = pmax; }
            else         { sumb[pi] += psum; maxb[pi] = fmaxf(maxb[pi], pmax); }
        }
        return;
    }

    // ============ gemm (MFMA f16, B straight from L2, no LDS) ============
    __builtin_amdgcn_s_setprio(0);
    const int gid = blockIdx.x - nScan;
    const int b   = gid & (BB - 1);
    const int dir = gid >> 9;
    const int chunk = dir ? (NC - 1 - cg) : cg;
    const int tbase = chunk * TC;
    if (tbase >= lens[b]) return;   // tile fully past len: gx never read
    const float* bias = dir ? bb : bf;
    const _Float16* Wg = Wt + (size_t)dir * (KS * 8 * 64 * 8);

    // A gather: lane l -> row = l&15 of wave's 16-row stripe, k-chunk (l>>4)*8
    const int w = tid >> 6, l = tid & 63;
    const int row = l & 15, kq = l >> 4;
    const int t0 = tbase + w * 16 + row;
    h8_t A[4];
    if (GATHER) {
        const int tok = text[b * TT + t0];
        const _Float16* ap = (const _Float16*)emb16 + (size_t)tok * 128 + kq * 8;
        #pragma unroll
        for (int ks = 0; ks < KS; ++ks) A[ks] = *(const h8_t*)(ap + ks * 32);
    } else {
        const _Float16* ap = (const _Float16*)Xh + ((size_t)b * TT + t0) * X1S + kq * 8;
        #pragma unroll
        for (int ks = 0; ks < KS; ++ks) A[ks] = *(const h8_t*)(ap + ks * 32);
    }

    f4_t acc[8] = {};
    #pragma unroll
    for (int ks = 0; ks < KS; ++ks)
        #pragma unroll
        for (int f = 0; f < 8; ++f) {
            const h8_t Bf = *(const h8_t*)(Wg + ((size_t)(ks * 8 + f) * 64 + l) * 8);
            acc[f] = __builtin_amdgcn_mfma_f32_16x16x32_f16(A[ks], Bf, acc[f], 0, 0, 0);
        }

    // epilogue: D[m=(l>>4)*4+reg][n=l&15]; per-element fp16 stores
    const size_t rowB = ((size_t)dir * BB + b) * TC;
    const int gb = l & 15, rq = l >> 4;
    #pragma unroll
    for (int f = 0; f < 8; ++f) {
        const int gate = f * 16 + gb;
        if (gate < GG) {
            const float bv = bias[gate];
            #pragma unroll
            for (int r = 0; r < 4; ++r) {
                const int tloc = w * 16 + rq * 4 + r;
                gxW[(rowB + tloc) * GG + gate] = __float2half(acc[f][r] + bv);
            }
        }
    }
}

// Precompute fp16 tables:
//  emb16 [50000][128] zero-padded; Wt16 = exact B-fragment images:
//  L0 [dir][ks<4][f<8][l<64][i<8], L1 [dir][ks<3][f<8][l<64][i<8];
//  Whh16 fp16 row-major [lay*2+dir][120][40]; plus zero out0 pad columns.
#define NE2 (50000 * 64)        // h2 units of padded emb16
#define NW0 (2*4*8*64)          // 4096 h8 units
#define NW1 (2*3*8*64)          // 3072 h8 units
#define NHH (4*120*20)          // 9600 h2 units
#define NP0 (BB*TT*8)           // h2 units of out0 pad (16 halfs/row)
__global__ __launch_bounds__(256) void prep_kernel(
    const float* __restrict__ emb,
    const float* __restrict__ Wih0f, const float* __restrict__ Wih0b,
    const float* __restrict__ Wih1f, const float* __restrict__ Wih1b,
    const float* __restrict__ Whh0f, const float* __restrict__ Whh0b,
    const float* __restrict__ Whh1f, const float* __restrict__ Whh1b,
    __half* __restrict__ emb16, _Float16* __restrict__ Wt16,
    _Float16* __restrict__ Whh16, __half* __restrict__ out0)
{
    const int gid = blockIdx.x * 256 + threadIdx.x;
    if (gid < NE2) {
        const int v = gid >> 6, q2 = gid & 63;
        const int k0 = q2 * 2;
        float x0 = 0.f, x1 = 0.f;
        if (k0 < EE) { x0 = emb[(size_t)v * EE + k0]; x1 = emb[(size_t)v * EE + k0 + 1]; }
        ((h2_t*)emb16)[(size_t)v * 64 + q2] = pack2_(x0, x1);
        return;
    }
    int e = gid - NE2;
    if (e < NP0) {              // zero out0 pad columns (halfs 80..95 per row)
        const int row = e >> 3, q = e & 7;
        ((h2_t*)out0)[(size_t)row * 48 + 40 + q] = pack2_(0.f, 0.f);
        return;
    }
    e -= NP0;
    if (e < NW0) {              // layer0 B-fragments, K=100 (pad 128)
        const int l = e & 63, f = (e >> 6) & 7, ks = (e >> 9) & 3, dir = e >> 11;
        const float* W = dir ? Wih0b : Wih0f;
        const int col = f * 16 + (l & 15);
        const int kb  = ks * 32 + (l >> 4) * 8;
        _Float16* dst = Wt16 + (size_t)e * 8;
        #pragma unroll
        for (int i = 0; i < 8; ++i) {
            const int k = kb + i;
            dst[i] = (_Float16)((col < GG && k < EE) ? W[(size_t)col * EE + k] : 0.f);
        }
        return;
    }
    e -= NW0;
    if (e < NW1) {              // layer1 B-fragments, K=80 (pad 96)
        const int l = e & 63, f = (e >> 6) & 7;
        const int t = e >> 9;               // 0..5 = dir*3 + ks
        const int ks = t % 3, dir = t / 3;
        const float* W = dir ? Wih1b : Wih1f;
        const int col = f * 16 + (l & 15);
        const int kb  = ks * 32 + (l >> 4) * 8;
        _Float16* dst = Wt16 + (size_t)(NW0 + e) * 8;
        #pragma unroll
        for (int i = 0; i < 8; ++i) {
            const int k = kb + i;
            dst[i] = (_Float16)((col < GG && k < 2*HH) ? W[(size_t)col * (2*HH) + k] : 0.f);
        }
        return;
    }
    e -= NW1;
    if (e < NHH) {              // Whh fp16, 4 x [120][40]
        const int ld = e / 2400, rem = e - ld * 2400;
        const int row2 = rem / 20, kk = rem - row2 * 20;
        const float* W = (ld == 0) ? Whh0f : (ld == 1) ? Whh0b
                       : (ld == 2) ? Whh1f : Whh1b;
        ((h2_t*)Whh16)[e] = pack2_(W[row2*HH + 2*kk], W[row2*HH + 2*kk + 1]);
    }
}

// pool_cat = [hb1, hf1, hb0, hf0, avg(80), max(80)] -> fc1(128) -> lrelu -> fc2(1)
__global__ __launch_bounds__(128) void fc_kernel(
    const float* __restrict__ hlast, const float* __restrict__ sumb,
    const float* __restrict__ maxb, const int* __restrict__ lens,
    const float* __restrict__ fc1W, const float* __restrict__ fc1b,
    const float* __restrict__ fc2W, const float* __restrict__ fc2b,
    float* __restrict__ out)
{
    __shared__ float pool[8 * HH];
    __shared__ float red[128];
    const int b = blockIdx.x, tid = threadIdx.x;
    if (tid < HH) {
        pool[tid]        = hlast[(size_t)(3*BB + b) * HH + tid]; // hb1
        pool[HH + tid]   = hlast[(size_t)(2*BB + b) * HH + tid]; // hf1
        pool[2*HH + tid] = hlast[(size_t)(1*BB + b) * HH + tid]; // hb0
        pool[3*HH + tid] = hlast[(size_t)(0*BB + b) * HH + tid]; // hf0
    }
    const float invLen = 1.0f / (float)lens[b];
    if (tid < 2*HH) {
        pool[4*HH + tid] = sumb[(size_t)b * 2*HH + tid] * invLen;
        pool[6*HH + tid] = maxb[(size_t)b * 2*HH + tid];
    }
    __syncthreads();
    float acc = fc1b[tid];
    for (int k = 0; k < 8*HH; ++k)
        acc = fmaf(pool[k], fc1W[(size_t)tid * (8*HH) + k], acc);
    float v = (acc >= 0.0f) ? acc : 0.01f * acc;
    red[tid] = v * fc2W[tid];
    __syncthreads();
    for (int s = 64; s > 0; s >>= 1) {
        if (tid < s) red[tid] += red[tid + s];
        __syncthreads();
    }
    if (tid == 0) out[b] = red[0] + fc2b[0];
}

extern "C" void kernel_launch(void* const* d_in, const int* in_sizes, int n_in,
                              void* d_out, int out_size, void* d_ws, size_t ws_size,
                              hipStream_t stream) {
    const int*   text  = (const int*)d_in[0];
    const int*   lens  = (const int*)d_in[1];
    const float* emb   = (const float*)d_in[2];
    const float* Wih0f = (const float*)d_in[3];
    const float* Whh0f = (const float*)d_in[4];
    const float* bih0f = (const float*)d_in[5];
    const float* bhh0f = (const float*)d_in[6];
    const float* Wih0b = (const float*)d_in[7];
    const float* Whh0b = (const float*)d_in[8];
    const float* bih0b = (const float*)d_in[9];
    const float* bhh0b = (const float*)d_in[10];
    const float* Wih1f = (const float*)d_in[11];
    const float* Whh1f = (const float*)d_in[12];
    const float* bih1f = (const float*)d_in[13];
    const float* bhh1f = (const float*)d_in[14];
    const float* Wih1b = (const float*)d_in[15];
    const float* Whh1b = (const float*)d_in[16];
    const float* bih1b = (const float*)d_in[17];
    const float* bhh1b = (const float*)d_in[18];
    const float* fc1W  = (const float*)d_in[19];
    const float* fc1b  = (const float*)d_in[20];
    const float* fc2W  = (const float*)d_in[21];
    const float* fc2b  = (const float*)d_in[22];
    float* out = (float*)d_out;

    // ws: gx dbuf fp16 | out0 fp16 (stride 96) | small | fp16 tables
    char* p = (char*)d_ws;
    const size_t gxB = (size_t)2 * BB * TC * GG * sizeof(__half);
    __half* gxb0  = (__half*)p;  p += gxB;
    __half* gxb1  = (__half*)p;  p += gxB;
    __half* out0  = (__half*)p;  p += (size_t)BB * TT * X1S * sizeof(__half);
    float*  hcar  = (float*)p;   p += (size_t)2 * BB * HH * sizeof(float);
    float*  hlast = (float*)p;   p += (size_t)4 * BB * HH * sizeof(float);
    float*  sumb  = (float*)p;   p += (size_t)BB * 2 * HH * sizeof(float);
    float*  maxb  = (float*)p;   p += (size_t)BB * 2 * HH * sizeof(float);
    __half*    emb16 = (__half*)p;    p += (size_t)50000 * 128 * sizeof(__half);
    _Float16*  Wt16  = (_Float16*)p;  p += (size_t)(NW0 + NW1) * 8 * sizeof(_Float16);
    _Float16*  Whh16 = (_Float16*)p;
    __half* gxb[2] = { gxb0, gxb1 };

    const int NG = BB * 2;       // 1024 gemm blocks (b, dir)
    const int NS = 256;          // 1024 chains / 4 waves per block

    // ---- precompute fp16 tables + out0 pad zeroing ----
    {
        const int total = NE2 + NP0 + NW0 + NW1 + NHH;
        prep_kernel<<<(total + 255) / 256, 256, 0, stream>>>(
            emb, Wih0f, Wih0b, Wih1f, Wih1b, Whh0f, Whh0b, Whh1f, Whh1b,
            emb16, Wt16, Whh16, out0);
    }

    // ---- layer 0 ----
    fused_kernel<EE, true><<<NG, 256, 0, stream>>>(0, 0, 0,
        text, emb16, nullptr, Wt16, bih0f, bih0b,
        gxb[0], gxb[0], Whh16, bhh0f, bhh0b,
        lens, out0, hcar, hlast, sumb, maxb);
    for (int ci = 1; ci < NC; ++ci)
        fused_kernel<EE, true><<<NS + NG, 256, 0, stream>>>(ci, ci - 1, NS,
            text, emb16, nullptr, Wt16, bih0f, bih0b,
            gxb[ci & 1], gxb[(ci - 1) & 1], Whh16, bhh0f, bhh0b,
            lens, out0, hcar, hlast, sumb, maxb);
    fused_kernel<EE, true><<<NS, 256, 0, stream>>>(0, NC - 1, NS,
        text, emb16, nullptr, Wt16, bih0f, bih0b,
        gxb[0], gxb[(NC - 1) & 1], Whh16, bhh0f, bhh0b,
        lens, out0, hcar, hlast, sumb, maxb);

    // ---- layer 1 ----
    fused_kernel<2*HH, false><<<NG, 256, 0, stream>>>(0, 0, 0,
        text, emb16, out0, Wt16 + (size_t)NW0 * 8, bih1f, bih1b,
        gxb[0], gxb[0], Whh16 + 9600, bhh1f, bhh1b,
        lens, out0, hcar, hlast, sumb, maxb);
    for (int ci = 1; ci < NC; ++ci)
        fused_kernel<2*HH, false><<<NS + NG, 256, 0, stream>>>(ci, ci - 1, NS,
            text, emb16, out0, Wt16 + (size_t)NW0 * 8, bih1f, bih1b,
            gxb[ci & 1], gxb[(ci - 1) & 1], Whh16 + 9600, bhh1f, bhh1b,
            lens, out0, hcar, hlast, sumb, maxb);
    fused_kernel<2*HH, false><<<NS, 256, 0, stream>>>(0, NC - 1, NS,
        text, emb16, out0, Wt16 + (size_t)NW0 * 8, bih1f, bih1b,
        gxb[0], gxb[(NC - 1) & 1], Whh16 + 9600, bhh1f, bhh1b,
        lens, out0, hcar, hlast, sumb, maxb);

    // ---- head ----
    fc_kernel<<<BB, 128, 0, stream>>>(hlast, sumb, maxb, lens,
        fc1W, fc1b, fc2W, fc2b, out);
}